// Round 2
// baseline (112.548 us; speedup 1.0000x reference)
//
#include <hip/hip_runtime.h>
#include <hip/hip_bf16.h>

#define EMB_DIM 128

// Kernel 1: start[n] = lower_bound(segment_ids, n) for n in [0, N]
__global__ void seg_starts_kernel(const int* __restrict__ seg, int E, int N,
                                  int* __restrict__ start) {
    int n = blockIdx.x * blockDim.x + threadIdx.x;
    if (n > N) return;
    int lo = 0, hi = E;
    while (lo < hi) {
        int mid = (lo + hi) >> 1;
        if (seg[mid] < n) lo = mid + 1; else hi = mid;
    }
    start[n] = lo;
}

// Kernel 2: one block (128 threads) per node; thread d owns column d.
__global__ void seg_mean_kernel(const float* __restrict__ W,
                                const int* __restrict__ idx,
                                const int* __restrict__ start,
                                float* __restrict__ out) {
    int n = blockIdx.x;
    int d = threadIdx.x;              // 0..127
    int s = start[n];
    int e = start[n + 1];
    float acc = 0.0f;
    int j = s;
    // 2-deep unroll for a bit of load ILP
    for (; j + 1 < e; j += 2) {
        int r0 = idx[j];
        int r1 = idx[j + 1];
        float a0 = W[(long long)r0 * EMB_DIM + d];
        float a1 = W[(long long)r1 * EMB_DIM + d];
        acc += a0;
        acc += a1;
    }
    if (j < e) {
        int r0 = idx[j];
        acc += W[(long long)r0 * EMB_DIM + d];
    }
    float cnt = (float)(e - s);
    out[n * EMB_DIM + d] = acc / fmaxf(cnt, 1.0f);
}

extern "C" void kernel_launch(void* const* d_in, const int* in_sizes, int n_in,
                              void* d_out, int out_size, void* d_ws, size_t ws_size,
                              hipStream_t stream) {
    const float* weight      = (const float*)d_in[0];
    const int*   neigh_idx   = (const int*)d_in[1];
    const int*   segment_ids = (const int*)d_in[2];
    // d_in[3] is num_nodes (device scalar) — derive host-side instead:
    int N = out_size / EMB_DIM;       // 10000
    int E = in_sizes[1];              // 320000

    int* start = (int*)d_ws;          // (N+1) ints

    {
        int threads = 256;
        int blocks = (N + 1 + threads - 1) / threads;
        seg_starts_kernel<<<blocks, threads, 0, stream>>>(segment_ids, E, N, start);
    }
    {
        seg_mean_kernel<<<N, EMB_DIM, 0, stream>>>(weight, neigh_idx, start, (float*)d_out);
    }
}

// Round 5
// 112.263 us; speedup vs baseline: 1.0025x; 1.0025x over previous
//
#include <hip/hip_runtime.h>
#include <hip/hip_bf16.h>

#define EMB_DIM 128

// Kernel 1: start[n] = lower_bound(segment_ids, n) for n in [0, N]
__global__ void seg_starts_kernel(const int* __restrict__ seg, int E, int N,
                                  int* __restrict__ start) {
    int n = blockIdx.x * blockDim.x + threadIdx.x;
    if (n > N) return;
    int lo = 0, hi = E;
    while (lo < hi) {
        int mid = (lo + hi) >> 1;
        if (seg[mid] < n) lo = mid + 1; else hi = mid;
    }
    start[n] = lo;
}

// Kernel 2: one 256-thread block per node.
//   group g = t/32 (8 edge-groups), lane c = t%32 (column quad: cols 4c..4c+3)
//   Each group accumulates rows j = s+g, s+g+8, ... as float4 loads
//   (32 lanes x 16B = one full 512B row per half-wave). LDS reduce across
//   the 8 groups, then group 0 scales by 1/count and writes out.
__global__ void seg_mean_kernel(const float* __restrict__ W,
                                const int* __restrict__ idx,
                                const int* __restrict__ start,
                                float* __restrict__ out) {
    int n = blockIdx.x;
    int t = threadIdx.x;          // 0..255
    int g = t >> 5;               // 0..7
    int c = t & 31;               // 0..31
    int s = start[n];
    int e = start[n + 1];

    float4 acc = make_float4(0.f, 0.f, 0.f, 0.f);
    for (int j = s + g; j < e; j += 8) {
        int r = idx[j];
        const float4* row = (const float4*)(W + (long long)r * EMB_DIM);
        float4 v = row[c];
        acc.x += v.x; acc.y += v.y; acc.z += v.z; acc.w += v.w;
    }

    __shared__ float4 red[8][32];
    red[g][c] = acc;
    __syncthreads();

    if (g == 0) {
        float4 a = red[0][c];
        #pragma unroll
        for (int gg = 1; gg < 8; ++gg) {
            float4 v = red[gg][c];
            a.x += v.x; a.y += v.y; a.z += v.z; a.w += v.w;
        }
        float inv = 1.0f / fmaxf((float)(e - s), 1.0f);
        float4 o = make_float4(a.x * inv, a.y * inv, a.z * inv, a.w * inv);
        ((float4*)(out + (long long)n * EMB_DIM))[c] = o;
    }
}

extern "C" void kernel_launch(void* const* d_in, const int* in_sizes, int n_in,
                              void* d_out, int out_size, void* d_ws, size_t ws_size,
                              hipStream_t stream) {
    const float* weight      = (const float*)d_in[0];
    const int*   neigh_idx   = (const int*)d_in[1];
    const int*   segment_ids = (const int*)d_in[2];
    int N = out_size / EMB_DIM;       // 10000
    int E = in_sizes[1];              // 320000

    int* start = (int*)d_ws;          // (N+1) ints

    {
        int threads = 256;
        int blocks = (N + 1 + threads - 1) / threads;
        seg_starts_kernel<<<blocks, threads, 0, stream>>>(segment_ids, E, N, start);
    }
    {
        seg_mean_kernel<<<N, 256, 0, stream>>>(weight, neigh_idx, start, (float*)d_out);
    }
}